// Round 3
// baseline (439.905 us; speedup 1.0000x reference)
//
#include <hip/hip_runtime.h>

#define NNODES 50000
#define NEDGES 800000
#define DIM 128
#define NGRAPHS 128
#define OUT1_STRIDE 384   // 3 layers * 128 concat along axis 1
#define OUT0_ELEMS (NGRAPHS * OUT1_STRIDE)
#define SCAN_CHUNK 512
#define ROWPAD 50048      // 64-aligned node row allocation (includes sentinel row N)

typedef unsigned int uint;
typedef unsigned short ushort;
typedef short bf16x8 __attribute__((ext_vector_type(8)));
typedef float f32x4 __attribute__((ext_vector_type(4)));

union U4 { uint4 u; bf16x8 h; };

__device__ inline uint rne_bf16(float f) {
    uint b = __float_as_uint(f);
    return (b + 0x7fffu + ((b >> 16) & 1u)) >> 16;
}
__device__ inline uint pack_bf16(float lo, float hi) {
    return rne_bf16(lo) | (rne_bf16(hi) << 16);
}
__device__ inline float blo(uint u) { return __uint_as_float(u << 16); }
__device__ inline float bhi(uint u) { return __uint_as_float(u & 0xffff0000u); }

// hb layout: BLOCKED by channel slice for L2 residency during aggregation.
//   slice s (0..3) = channels [32s, 32s+32); per slice: ROWPAD rows x 64 B.
//   slice buffer = 3.2 MB < 4 MB per-XCD L2 -> each XCD caches the whole slice.

// ---------- pre: W swizzle (blocks 0..23) + rowcnt zero + hb sentinel zero ----------
__global__ __launch_bounds__(256) void k_pre(const float* __restrict__ W0,
                                             const float* __restrict__ W1,
                                             const float* __restrict__ W2,
                                             uint* __restrict__ wz,
                                             int* __restrict__ rowcnt,
                                             uint* __restrict__ hb, int N) {
    if (blockIdx.x >= 24) {
        int i = (blockIdx.x - 24) * 256 + threadIdx.x;
        if (i < N) rowcnt[i] = 0;
        if (i < 64)  // zero sentinel row N in all 4 slices (16 uints each)
            hb[(size_t)(i >> 4) * (ROWPAD * 16) + (size_t)N * 16 + (i & 15)] = 0;
        return;
    }
    int layer = blockIdx.x >> 3;
    const float* W = (layer == 0) ? W0 : ((layer == 1) ? W1 : W2);
    int t = (blockIdx.x & 7) * 256 + threadIdx.x;  // chunk id 0..2047
    int f = t >> 6, lane = t & 63;
    int kb = f >> 3, nt = f & 7;
    int q = lane >> 4, m = lane & 15;
    int col = nt * 16 + m;
    uint v[8];
#pragma unroll
    for (int j = 0; j < 8; ++j)
        v[j] = rne_bf16(W[(kb * 32 + q * 8 + j) * 128 + col]);
    uint4 o;
    o.x = v[0] | (v[1] << 16);
    o.y = v[2] | (v[3] << 16);
    o.z = v[4] | (v[5] << 16);
    o.w = v[6] | (v[7] << 16);
    ((uint4*)wz)[layer * 2048 + t] = o;
}

// ---------- CSR build ----------
__global__ void k_count(const int* __restrict__ dst, int* __restrict__ rowcnt,
                        int* __restrict__ rank, int E) {
    int e = blockIdx.x * blockDim.x + threadIdx.x;
    if (e < E) rank[e] = atomicAdd(&rowcnt[dst[e]], 1);
}

__global__ __launch_bounds__(512) void k_sum(const int* __restrict__ cnt,
                                             int* __restrict__ bsum,
                                             float* __restrict__ dinv, int n) {
    __shared__ int red[512];
    int t = threadIdx.x;
    int i = blockIdx.x * SCAN_CHUNK + t;
    int c = (i < n) ? cnt[i] : 0;
    if (i < n) dinv[i] = rsqrtf((float)c + 1.0f);  // +1 self-loop
    red[t] = c;
    __syncthreads();
    for (int off = 256; off > 0; off >>= 1) {
        if (t < off) red[t] += red[t + off];
        __syncthreads();
    }
    if (t == 0) bsum[blockIdx.x] = red[0];
}

__global__ __launch_bounds__(128) void k_scanb(const int* __restrict__ bsum,
                                               int* __restrict__ boff, int nb) {
    __shared__ int s[128];
    int t = threadIdx.x;
    int v = (t < nb) ? bsum[t] : 0;
    s[t] = v;
    __syncthreads();
    for (int off = 1; off < 128; off <<= 1) {
        int u = (t >= off) ? s[t - off] : 0;
        __syncthreads();
        s[t] += u;
        __syncthreads();
    }
    boff[t] = s[t] - v;  // exclusive
    if (t == nb - 1) boff[nb] = s[t];
}

__global__ __launch_bounds__(512) void k_writeptr(const int* __restrict__ cnt,
                                                  const int* __restrict__ boff,
                                                  int* __restrict__ rowptr, int n) {
    __shared__ int s[512];
    int t = threadIdx.x;
    int i = blockIdx.x * SCAN_CHUNK + t;
    int v = (i < n) ? cnt[i] : 0;
    s[t] = v;
    __syncthreads();
    for (int off = 1; off < 512; off <<= 1) {
        int u = (t >= off) ? s[t - off] : 0;
        __syncthreads();
        s[t] += u;
        __syncthreads();
    }
    if (i < n) rowptr[i] = boff[blockIdx.x] + s[t] - v;
    if (i == n - 1) rowptr[n] = boff[blockIdx.x] + s[t];
}

__global__ void k_fill(const int* __restrict__ src, const int* __restrict__ dst,
                       const int* __restrict__ rowptr, const int* __restrict__ rank,
                       int* __restrict__ csr_src, int E) {
    int e = blockIdx.x * blockDim.x + threadIdx.x;
    if (e < E) {
        int d = dst[e];
        csr_src[rowptr[d] + rank[e]] = src[e];
    }
}

// ---------- MFMA GEMM: hb[slice][M x 32ch bf16] = dinv[row] * (A @ W) ----------
__global__ __launch_bounds__(256) void k_gemm(const float* __restrict__ A, int lda,
                                              const uint* __restrict__ Wswz,
                                              const float* __restrict__ dinv,
                                              uint* __restrict__ hb, int M) {
    __shared__ uint4 wsw[2048];       // 32 KB swizzled W
    __shared__ ushort cbuf[64 * 128]; // 16 KB C bounce
    int tid = threadIdx.x;
#pragma unroll
    for (int i = 0; i < 8; ++i)
        wsw[i * 256 + tid] = ((const uint4*)Wswz)[i * 256 + tid];
    __syncthreads();
    int wave = tid >> 6, lane = tid & 63;
    int q = lane >> 4, m = lane & 15;
    int row0 = blockIdx.x * 64 + wave * 16;
    int arow = min(row0 + m, M - 1);       // clamp; stores are guarded
    const float* Ar = A + (size_t)arow * lda + q * 8;
    f32x4 zero = {0.0f, 0.0f, 0.0f, 0.0f};
    f32x4 acc[8];
#pragma unroll
    for (int i = 0; i < 8; ++i) acc[i] = zero;
#pragma unroll
    for (int kb = 0; kb < 4; ++kb) {
        float4 f0 = *(const float4*)(Ar + kb * 32);
        float4 f1 = *(const float4*)(Ar + kb * 32 + 4);
        U4 a;
        a.u.x = pack_bf16(f0.x, f0.y);
        a.u.y = pack_bf16(f0.z, f0.w);
        a.u.z = pack_bf16(f1.x, f1.y);
        a.u.w = pack_bf16(f1.z, f1.w);
#pragma unroll
        for (int nt = 0; nt < 8; ++nt) {
            U4 b; b.u = wsw[(kb * 8 + nt) * 64 + lane];
            acc[nt] = __builtin_amdgcn_mfma_f32_16x16x32_bf16(a.h, b.h, acc[nt], 0, 0, 0);
        }
    }
    // C/D: col = nt*16 + m, row = q*4 + r ; scale row r by dinv[row0+q*4+r]
    float dv[4];
#pragma unroll
    for (int r = 0; r < 4; ++r)
        dv[r] = dinv[min(row0 + q * 4 + r, M - 1)];
    ushort* cw = cbuf + wave * 16 * 128;
#pragma unroll
    for (int nt = 0; nt < 8; ++nt)
#pragma unroll
        for (int r = 0; r < 4; ++r)
            cw[(q * 4 + r) * 128 + nt * 16 + m] = (ushort)rne_bf16(acc[nt][r] * dv[r]);
    __syncthreads();
    const uint4* cr4 = (const uint4*)cbuf;
    uint4* hb4 = (uint4*)hb;
#pragma unroll
    for (int i = 0; i < 4; ++i) {
        int c = (wave * 256) + i * 64 + lane;  // chunk: row = c>>4, piece = c&15
        int grow = blockIdx.x * 64 + (c >> 4);
        int p = c & 15;                        // 16B piece = channels 8p..8p+7
        uint4 v = cr4[c];
        if (grow < M)                          // blocked: slice p>>2, sub-piece p&3
            hb4[(size_t)(p >> 2) * (ROWPAD * 4) + (size_t)grow * 4 + (p & 3)] = v;
    }
}

// ---------- fused aggregate + bias + relu + write out1 (channel-sliced) ----------
// grid = (ceil(N/4), 4): blockIdx.y = channel slice (x-fastest dispatch keeps the
// 3.2 MB slice L2-resident per phase). One wave per node per slice.
// Lane layout: g = lane>>2 owns edge slot (16 edges/gather instr), q4 = lane&3 owns
// 8 channels (uint4 = 16 B of the 64 B slice row). No shuffles in the edge loop.
__global__ __launch_bounds__(256) void k_agg(const uint* __restrict__ hb,
                                             const int* __restrict__ rowptr,
                                             const int* __restrict__ csr_src,
                                             const float* __restrict__ dinv,
                                             const float* __restrict__ bias,
                                             float* __restrict__ out1,
                                             int N, int layer) {
    int wave = threadIdx.x >> 6;
    int lane = threadIdx.x & 63;
    int slice = blockIdx.y;
    int n = blockIdx.x * 4 + wave;
    if (n >= N) return;
    int g = lane >> 2;    // edge slot 0..15
    int q4 = lane & 3;    // 16B sub-piece -> channels slice*32 + q4*8 .. +7
    const uint4* hb4 = (const uint4*)hb + (size_t)slice * (ROWPAD * 4);

    // self-loop (hb already dinv[n]-scaled); counted once via group 0
    uint4 su = hb4[(size_t)n * 4 + q4];
    float sel = (g == 0) ? 1.0f : 0.0f;
    float a0 = sel * blo(su.x), a1 = sel * bhi(su.x);
    float a2 = sel * blo(su.y), a3 = sel * bhi(su.y);
    float a4 = sel * blo(su.z), a5 = sel * bhi(su.z);
    float a6 = sel * blo(su.w), a7 = sel * bhi(su.w);

    int beg = rowptr[n], end = rowptr[n + 1];
    int base = beg;
    for (; base + 32 <= end; base += 32) {   // guard-free: 32 edges / iter
        int s0 = csr_src[base + g];
        int s1 = csr_src[base + 16 + g];
        uint4 u0 = hb4[(size_t)s0 * 4 + q4];
        uint4 u1 = hb4[(size_t)s1 * 4 + q4];
        a0 += blo(u0.x); a1 += bhi(u0.x); a2 += blo(u0.y); a3 += bhi(u0.y);
        a4 += blo(u0.z); a5 += bhi(u0.z); a6 += blo(u0.w); a7 += bhi(u0.w);
        a0 += blo(u1.x); a1 += bhi(u1.x); a2 += blo(u1.y); a3 += bhi(u1.y);
        a4 += blo(u1.z); a5 += bhi(u1.z); a6 += blo(u1.w); a7 += bhi(u1.w);
    }
    for (; base < end; base += 16) {         // remainder: sentinel-masked
        int e = base + g;
        int s0 = (e < end) ? csr_src[e] : N;
        uint4 u0 = hb4[(size_t)s0 * 4 + q4];
        a0 += blo(u0.x); a1 += bhi(u0.x); a2 += blo(u0.y); a3 += bhi(u0.y);
        a4 += blo(u0.z); a5 += bhi(u0.z); a6 += blo(u0.w); a7 += bhi(u0.w);
    }

    // reduce across the 16 edge groups (lane bits 2..5)
#pragma unroll
    for (int d = 4; d < 64; d <<= 1) {
        a0 += __shfl_xor(a0, d); a1 += __shfl_xor(a1, d);
        a2 += __shfl_xor(a2, d); a3 += __shfl_xor(a3, d);
        a4 += __shfl_xor(a4, d); a5 += __shfl_xor(a5, d);
        a6 += __shfl_xor(a6, d); a7 += __shfl_xor(a7, d);
    }

    if (g == 0) {   // lanes 0..3 write 8 channels each = 32 ch of this slice
        float din = dinv[n];
        int c0 = slice * 32 + q4 * 8;
        float4 b0 = *(const float4*)(bias + c0);
        float4 b1 = *(const float4*)(bias + c0 + 4);
        float4 o0, o1;
        o0.x = fmaxf(din * a0 + b0.x, 0.0f);
        o0.y = fmaxf(din * a1 + b0.y, 0.0f);
        o0.z = fmaxf(din * a2 + b0.z, 0.0f);
        o0.w = fmaxf(din * a3 + b0.w, 0.0f);
        o1.x = fmaxf(din * a4 + b1.x, 0.0f);
        o1.y = fmaxf(din * a5 + b1.y, 0.0f);
        o1.z = fmaxf(din * a6 + b1.z, 0.0f);
        o1.w = fmaxf(din * a7 + b1.w, 0.0f);
        float* op = out1 + (size_t)n * OUT1_STRIDE + layer * DIM + c0;
        *(float4*)op = o0;
        *(float4*)(op + 4) = o1;
    }
}

// ---------- mean-pool: 3 blocks per graph (128-ch chunk each), 2 row-slices ----------
__global__ __launch_bounds__(256) void k_pool(const float* __restrict__ out1,
                                              const int* __restrict__ batch,
                                              float* __restrict__ out0, int N) {
    int g = blockIdx.x / 3;
    int chunk = blockIdx.x % 3;
    int lo = 0, hi = N;
    while (lo < hi) { int mid = (lo + hi) >> 1; if (batch[mid] < g) lo = mid + 1; else hi = mid; }
    int beg = lo;
    hi = N;
    while (lo < hi) { int mid = (lo + hi) >> 1; if (batch[mid] < g + 1) lo = mid + 1; else hi = mid; }
    int end = lo;
    int t = threadIdx.x;
    int ch = t & 127;
    int slice = t >> 7;            // 0 or 1: even/odd rows
    const float* p = out1 + (size_t)chunk * 128 + ch;
    float acc = 0.0f;
    int i = beg + slice;
    for (; i + 6 < end; i += 8) {  // stride-2 rows, 4-way MLP unroll
        float a0 = p[(size_t)i * OUT1_STRIDE];
        float a1 = p[(size_t)(i + 2) * OUT1_STRIDE];
        float a2 = p[(size_t)(i + 4) * OUT1_STRIDE];
        float a3 = p[(size_t)(i + 6) * OUT1_STRIDE];
        acc += (a0 + a1) + (a2 + a3);
    }
    for (; i < end; i += 2) acc += p[(size_t)i * OUT1_STRIDE];
    __shared__ float red[256];
    red[t] = acc;
    __syncthreads();
    if (t < 128) {
        float tot = red[t] + red[t + 128];
        float cnt = (float)(end - beg);
        out0[(size_t)g * OUT1_STRIDE + chunk * 128 + t] = tot / fmaxf(cnt, 1.0f);
    }
}

extern "C" void kernel_launch(void* const* d_in, const int* in_sizes, int n_in,
                              void* d_out, int out_size, void* d_ws, size_t ws_size,
                              hipStream_t stream) {
    const float* x     = (const float*)d_in[0];
    const int*   ei    = (const int*)d_in[1];
    const int*   batch = (const int*)d_in[2];
    const float* W0 = (const float*)d_in[3];
    const float* b0 = (const float*)d_in[4];
    const float* W1 = (const float*)d_in[5];
    const float* b1 = (const float*)d_in[6];
    const float* W2 = (const float*)d_in[7];
    const float* b2 = (const float*)d_in[8];
    (void)n_in; (void)ws_size; (void)out_size;

    const int E = in_sizes[1] / 2;
    const int N = in_sizes[2];
    const int* src = ei;
    const int* dst = ei + E;

    char* ws = (char*)d_ws;
    uint*  hb       = (uint*)ws;  ws += (size_t)ROWPAD * 64 * 4;   // 4-slice blocked bf16
    uint*  wz       = (uint*)ws;  ws += 3 * 8192 * 4;              // swizzled W ×3
    float* dinv     = (float*)ws; ws += 50016 * 4;
    int*   rowcnt   = (int*)ws;   ws += 50016 * 4;
    int*   rowptr   = (int*)ws;   ws += 50016 * 4;
    int*   rank     = (int*)ws;   ws += (size_t)NEDGES * 4;
    int*   csr_src  = (int*)ws;   ws += (size_t)NEDGES * 4;
    int*   bsum     = (int*)ws;   ws += 256 * 4;
    int*   boff     = (int*)ws;   ws += 256 * 4;

    float* out0 = (float*)d_out;                 // [128, 384] pooled
    float* out1 = (float*)d_out + OUT0_ELEMS;    // [50000, 384] per-layer features

    const int nb  = (N + SCAN_CHUNK - 1) / SCAN_CHUNK;  // 98
    const int nbz = 24 + (N + 255) / 256;               // pre: 24 wswz + zero blocks

    k_pre     <<<nbz, 256, 0, stream>>>(W0, W1, W2, wz, rowcnt, hb, N);
    k_count   <<<(E + 255) / 256, 256, 0, stream>>>(dst, rowcnt, rank, E);
    k_sum     <<<nb, 512, 0, stream>>>(rowcnt, bsum, dinv, N);
    k_scanb   <<<1, 128, 0, stream>>>(bsum, boff, nb);
    k_writeptr<<<nb, 512, 0, stream>>>(rowcnt, boff, rowptr, N);
    k_fill    <<<(E + 255) / 256, 256, 0, stream>>>(src, dst, rowptr, rank, csr_src, E);

    const float* bs[3] = {b0, b1, b2};
    const int ngb = (N + 63) / 64;   // 782 gemm blocks
    for (int l = 0; l < 3; ++l) {
        const float* Ain = (l == 0) ? x : (out1 + (size_t)(l - 1) * DIM);
        int lda          = (l == 0) ? DIM : OUT1_STRIDE;
        k_gemm<<<ngb, 256, 0, stream>>>(Ain, lda, wz + l * 8192, dinv, hb, N);
        k_agg <<<dim3((N + 3) / 4, 4), 256, 0, stream>>>(hb, rowptr, csr_src, dinv,
                                                         bs[l], out1, N, l);
    }
    k_pool<<<NGRAPHS * 3, 256, 0, stream>>>(out1, batch, out0, N);
}

// Round 6
// 362.900 us; speedup vs baseline: 1.2122x; 1.2122x over previous
//
#include <hip/hip_runtime.h>

#define NNODES 50000
#define NEDGES 800000
#define DIM 128
#define NGRAPHS 128
#define OUT1_STRIDE 384   // 3 layers * 128 concat along axis 1
#define OUT0_ELEMS (NGRAPHS * OUT1_STRIDE)
#define SCAN_CHUNK 512
#define ROWPAD 50048      // 64-aligned node row allocation (includes sentinel row N)

typedef unsigned int uint;
typedef unsigned short ushort;
typedef short bf16x8 __attribute__((ext_vector_type(8)));
typedef float f32x4 __attribute__((ext_vector_type(4)));
typedef float f32x2 __attribute__((ext_vector_type(2)));  // clang vector: nontemporal-store OK

union U4 { uint4 u; bf16x8 h; };

__device__ inline uint rne_bf16(float f) {
    uint b = __float_as_uint(f);
    return (b + 0x7fffu + ((b >> 16) & 1u)) >> 16;
}
__device__ inline uint pack_bf16(float lo, float hi) {
    return rne_bf16(lo) | (rne_bf16(hi) << 16);
}
__device__ inline float blo(uint u) { return __uint_as_float(u << 16); }
__device__ inline float bhi(uint u) { return __uint_as_float(u & 0xffff0000u); }

// ---------- pre: W swizzle (blocks 0..23) + rowcnt zero + hb sentinel zero ----------
// W -> MFMA B-fragment bf16: frag f = kblk*8+ntile, lane, j:
//   value = W[kblk*32 + (lane>>4)*8 + j][ntile*16 + (lane&15)]
__global__ __launch_bounds__(256) void k_pre(const float* __restrict__ W0,
                                             const float* __restrict__ W1,
                                             const float* __restrict__ W2,
                                             uint* __restrict__ wz,
                                             int* __restrict__ rowcnt,
                                             uint* __restrict__ hb, int N) {
    if (blockIdx.x >= 24) {
        int i = (blockIdx.x - 24) * 256 + threadIdx.x;
        if (i < N) rowcnt[i] = 0;
        if (i < 64) hb[(size_t)N * 64 + i] = 0;  // sentinel row for masked gathers
        return;
    }
    int layer = blockIdx.x >> 3;
    const float* W = (layer == 0) ? W0 : ((layer == 1) ? W1 : W2);
    int t = (blockIdx.x & 7) * 256 + threadIdx.x;  // chunk id 0..2047
    int f = t >> 6, lane = t & 63;
    int kb = f >> 3, nt = f & 7;
    int q = lane >> 4, m = lane & 15;
    int col = nt * 16 + m;
    uint v[8];
#pragma unroll
    for (int j = 0; j < 8; ++j)
        v[j] = rne_bf16(W[(kb * 32 + q * 8 + j) * 128 + col]);
    uint4 o;
    o.x = v[0] | (v[1] << 16);
    o.y = v[2] | (v[3] << 16);
    o.z = v[4] | (v[5] << 16);
    o.w = v[6] | (v[7] << 16);
    ((uint4*)wz)[layer * 2048 + t] = o;
}

// ---------- CSR build ----------
__global__ void k_count(const int* __restrict__ dst, int* __restrict__ rowcnt, int E) {
    int e = blockIdx.x * blockDim.x + threadIdx.x;
    if (e < E) atomicAdd(&rowcnt[dst[e]], 1);
}

__global__ __launch_bounds__(512) void k_sum(const int* __restrict__ cnt,
                                             int* __restrict__ bsum,
                                             float* __restrict__ dinv, int n) {
    __shared__ int red[512];
    int t = threadIdx.x;
    int i = blockIdx.x * SCAN_CHUNK + t;
    int c = (i < n) ? cnt[i] : 0;
    if (i < n) dinv[i] = rsqrtf((float)c + 1.0f);  // +1 self-loop
    red[t] = c;
    __syncthreads();
    for (int off = 256; off > 0; off >>= 1) {
        if (t < off) red[t] += red[t + off];
        __syncthreads();
    }
    if (t == 0) bsum[blockIdx.x] = red[0];
}

// merged: per-block 512-scan + in-kernel 128-wide bsum scan (replaces k_scanb).
// writes rowptr AND rowcur (atomic fill cursor copy).
__global__ __launch_bounds__(512) void k_writeptr(const int* __restrict__ cnt,
                                                  const int* __restrict__ bsum,
                                                  int* __restrict__ rowptr,
                                                  int* __restrict__ rowcur,
                                                  int n, int nb) {
    __shared__ int s[512];
    __shared__ int sb[128];
    int t = threadIdx.x;
    if (t < 128) sb[t] = (t < nb) ? bsum[t] : 0;
    __syncthreads();
    for (int off = 1; off < 128; off <<= 1) {
        int u = (t < 128 && t >= off) ? sb[t - off] : 0;
        __syncthreads();
        if (t < 128) sb[t] += u;
        __syncthreads();
    }
    int boffb = (blockIdx.x == 0) ? 0 : sb[blockIdx.x - 1];  // exclusive block offset
    int i = blockIdx.x * SCAN_CHUNK + t;
    int v = (i < n) ? cnt[i] : 0;
    s[t] = v;
    __syncthreads();
    for (int off = 1; off < 512; off <<= 1) {
        int u = (t >= off) ? s[t - off] : 0;
        __syncthreads();
        s[t] += u;
        __syncthreads();
    }
    if (i < n) {
        int p = boffb + s[t] - v;
        rowptr[i] = p;
        rowcur[i] = p;
    }
    if (i == n - 1) rowptr[n] = boffb + s[t];
}

__global__ void k_fill(const int* __restrict__ src, const int* __restrict__ dst,
                       int* __restrict__ rowcur, int* __restrict__ csr_src, int E) {
    int e = blockIdx.x * blockDim.x + threadIdx.x;
    if (e < E) {
        int pos = atomicAdd(&rowcur[dst[e]], 1);
        csr_src[pos] = src[e];
    }
}

// ---------- MFMA GEMM: hb[M x 128 bf16] = dinv[row] * (A[M x 128 f32] @ W) ----------
__global__ __launch_bounds__(256) void k_gemm(const float* __restrict__ A, int lda,
                                              const uint* __restrict__ Wswz,
                                              const float* __restrict__ dinv,
                                              uint* __restrict__ hb, int M) {
    __shared__ uint4 wsw[2048];       // 32 KB swizzled W
    __shared__ ushort cbuf[64 * 128]; // 16 KB C bounce
    int tid = threadIdx.x;
#pragma unroll
    for (int i = 0; i < 8; ++i)
        wsw[i * 256 + tid] = ((const uint4*)Wswz)[i * 256 + tid];
    __syncthreads();
    int wave = tid >> 6, lane = tid & 63;
    int q = lane >> 4, m = lane & 15;
    int row0 = blockIdx.x * 64 + wave * 16;
    int arow = min(row0 + m, M - 1);       // clamp; stores are guarded
    const float* Ar = A + (size_t)arow * lda + q * 8;
    f32x4 zero = {0.0f, 0.0f, 0.0f, 0.0f};
    f32x4 acc[8];
#pragma unroll
    for (int i = 0; i < 8; ++i) acc[i] = zero;
#pragma unroll
    for (int kb = 0; kb < 4; ++kb) {
        float4 f0 = *(const float4*)(Ar + kb * 32);
        float4 f1 = *(const float4*)(Ar + kb * 32 + 4);
        U4 a;
        a.u.x = pack_bf16(f0.x, f0.y);
        a.u.y = pack_bf16(f0.z, f0.w);
        a.u.z = pack_bf16(f1.x, f1.y);
        a.u.w = pack_bf16(f1.z, f1.w);
#pragma unroll
        for (int nt = 0; nt < 8; ++nt) {
            U4 b; b.u = wsw[(kb * 8 + nt) * 64 + lane];
            acc[nt] = __builtin_amdgcn_mfma_f32_16x16x32_bf16(a.h, b.h, acc[nt], 0, 0, 0);
        }
    }
    // C/D: col = nt*16 + m, row = q*4 + r ; scale row r by dinv[row0+q*4+r]
    float dv[4];
#pragma unroll
    for (int r = 0; r < 4; ++r)
        dv[r] = dinv[min(row0 + q * 4 + r, M - 1)];
    ushort* cw = cbuf + wave * 16 * 128;
#pragma unroll
    for (int nt = 0; nt < 8; ++nt)
#pragma unroll
        for (int r = 0; r < 4; ++r)
            cw[(q * 4 + r) * 128 + nt * 16 + m] = (ushort)rne_bf16(acc[nt][r] * dv[r]);
    __syncthreads();
    const uint4* cr4 = (const uint4*)cbuf;
#pragma unroll
    for (int i = 0; i < 4; ++i) {
        int c = (wave * 256) + i * 64 + lane;  // chunk: row = c>>4, piece = c&15
        int grow = blockIdx.x * 64 + (c >> 4);
        uint4 v = cr4[c];
        if (grow < M) ((uint4*)hb)[(size_t)grow * 16 + (c & 15)] = v;
    }
}

// ---------- fused aggregate + bias + relu + write out1 ----------
// one wave per node (R2 geometry: g16 = lane>>4 edge slot, m16 = lane&15 owns 16B
// of the 256B row; 4 full-row gathers in flight). csr indices via ONE aligned
// int4 load per 16 edges (quad-masked against [beg,end); sentinel row N absorbs
// masked slots). Channel-paired float2 accumulation (v_pk_add_f32 friendly).
__global__ __launch_bounds__(256) void k_agg(const uint* __restrict__ hb,
                                             const int* __restrict__ rowptr,
                                             const int* __restrict__ csr_src,
                                             const float* __restrict__ dinv,
                                             const float* __restrict__ bias,
                                             float* __restrict__ out1,
                                             int N, int layer) {
    int wave = threadIdx.x >> 6;
    int lane = threadIdx.x & 63;
    int n = blockIdx.x * 4 + wave;
    if (n >= N) return;
    int g16 = lane >> 4;
    int m16 = lane & 15;
    const uint4* hb4 = (const uint4*)hb;

    int beg = rowptr[n], end = rowptr[n + 1];
    uint4 su = hb4[(size_t)n * 16 + m16];   // self-loop (already dinv[n]-scaled)

    float2 a0, a1, a2, a3;                  // 8 channels as 4 pairs
    float sel = (g16 == 0) ? 1.0f : 0.0f;
    a0 = make_float2(sel * blo(su.x), sel * bhi(su.x));
    a1 = make_float2(sel * blo(su.y), sel * bhi(su.y));
    a2 = make_float2(sel * blo(su.z), sel * bhi(su.z));
    a3 = make_float2(sel * blo(su.w), sel * bhi(su.w));

    const int4* csr4 = (const int4*)csr_src;
    int q0 = beg >> 2;
    int qn = (end + 3) >> 2;                 // one past last quad
    for (int q = q0; q < qn; q += 4) {
        int qe = q + g16;                    // this slot's quad (may overrun: masked)
        int4 sv = csr4[qe];                  // csr_src padded +64 ints
        int e0 = qe * 4;
        int s0 = (e0     >= beg && e0     < end) ? sv.x : N;
        int s1 = (e0 + 1 >= beg && e0 + 1 < end) ? sv.y : N;
        int s2 = (e0 + 2 >= beg && e0 + 2 < end) ? sv.z : N;
        int s3 = (e0 + 3 >= beg && e0 + 3 < end) ? sv.w : N;
        uint4 u0 = hb4[(size_t)s0 * 16 + m16];
        uint4 u1 = hb4[(size_t)s1 * 16 + m16];
        uint4 u2 = hb4[(size_t)s2 * 16 + m16];
        uint4 u3 = hb4[(size_t)s3 * 16 + m16];
        a0.x += blo(u0.x); a0.y += bhi(u0.x);
        a1.x += blo(u0.y); a1.y += bhi(u0.y);
        a2.x += blo(u0.z); a2.y += bhi(u0.z);
        a3.x += blo(u0.w); a3.y += bhi(u0.w);
        a0.x += blo(u1.x); a0.y += bhi(u1.x);
        a1.x += blo(u1.y); a1.y += bhi(u1.y);
        a2.x += blo(u1.z); a2.y += bhi(u1.z);
        a3.x += blo(u1.w); a3.y += bhi(u1.w);
        a0.x += blo(u2.x); a0.y += bhi(u2.x);
        a1.x += blo(u2.y); a1.y += bhi(u2.y);
        a2.x += blo(u2.z); a2.y += bhi(u2.z);
        a3.x += blo(u2.w); a3.y += bhi(u2.w);
        a0.x += blo(u3.x); a0.y += bhi(u3.x);
        a1.x += blo(u3.y); a1.y += bhi(u3.y);
        a2.x += blo(u3.z); a2.y += bhi(u3.z);
        a3.x += blo(u3.w); a3.y += bhi(u3.w);
    }

    // cross-slot reduce: groups 0..3 hold partials of the same 8 channels
#pragma unroll
    for (int d = 16; d < 64; d <<= 1) {
        a0.x += __shfl_xor(a0.x, d); a0.y += __shfl_xor(a0.y, d);
        a1.x += __shfl_xor(a1.x, d); a1.y += __shfl_xor(a1.y, d);
        a2.x += __shfl_xor(a2.x, d); a2.y += __shfl_xor(a2.y, d);
        a3.x += __shfl_xor(a3.x, d); a3.y += __shfl_xor(a3.y, d);
    }

    // lane writes channel pair c = m16*8 + g16*2
    float2 pr = (g16 == 0) ? a0 : (g16 == 1) ? a1 : (g16 == 2) ? a2 : a3;
    float din = dinv[n];
    float2 b = ((const float2*)bias)[m16 * 4 + g16];
    f32x2 o;
    o.x = fmaxf(din * pr.x + b.x, 0.0f);
    o.y = fmaxf(din * pr.y + b.y, 0.0f);
    size_t o1 = (size_t)n * OUT1_STRIDE + layer * DIM + (m16 * 8 + g16 * 2);
    __builtin_nontemporal_store(o, (f32x2*)(out1 + o1));
}

// ---------- mean-pool: 3 blocks per graph (128-ch chunk each), 2 row-slices ----------
__global__ __launch_bounds__(256) void k_pool(const float* __restrict__ out1,
                                              const int* __restrict__ batch,
                                              float* __restrict__ out0, int N) {
    int g = blockIdx.x / 3;
    int chunk = blockIdx.x % 3;
    int lo = 0, hi = N;
    while (lo < hi) { int mid = (lo + hi) >> 1; if (batch[mid] < g) lo = mid + 1; else hi = mid; }
    int beg = lo;
    hi = N;
    while (lo < hi) { int mid = (lo + hi) >> 1; if (batch[mid] < g + 1) lo = mid + 1; else hi = mid; }
    int end = lo;
    int t = threadIdx.x;
    int ch = t & 127;
    int slice = t >> 7;            // 0 or 1: even/odd rows
    const float* p = out1 + (size_t)chunk * 128 + ch;
    float acc = 0.0f;
    int i = beg + slice;
    for (; i + 6 < end; i += 8) {  // stride-2 rows, 4-way MLP unroll
        float a0 = p[(size_t)i * OUT1_STRIDE];
        float a1 = p[(size_t)(i + 2) * OUT1_STRIDE];
        float a2 = p[(size_t)(i + 4) * OUT1_STRIDE];
        float a3 = p[(size_t)(i + 6) * OUT1_STRIDE];
        acc += (a0 + a1) + (a2 + a3);
    }
    for (; i < end; i += 2) acc += p[(size_t)i * OUT1_STRIDE];
    __shared__ float red[256];
    red[t] = acc;
    __syncthreads();
    if (t < 128) {
        float tot = red[t] + red[t + 128];
        float cnt = (float)(end - beg);
        out0[(size_t)g * OUT1_STRIDE + chunk * 128 + t] = tot / fmaxf(cnt, 1.0f);
    }
}

extern "C" void kernel_launch(void* const* d_in, const int* in_sizes, int n_in,
                              void* d_out, int out_size, void* d_ws, size_t ws_size,
                              hipStream_t stream) {
    const float* x     = (const float*)d_in[0];
    const int*   ei    = (const int*)d_in[1];
    const int*   batch = (const int*)d_in[2];
    const float* W0 = (const float*)d_in[3];
    const float* b0 = (const float*)d_in[4];
    const float* W1 = (const float*)d_in[5];
    const float* b1 = (const float*)d_in[6];
    const float* W2 = (const float*)d_in[7];
    const float* b2 = (const float*)d_in[8];
    (void)n_in; (void)ws_size; (void)out_size;

    const int E = in_sizes[1] / 2;
    const int N = in_sizes[2];
    const int* src = ei;
    const int* dst = ei + E;

    char* ws = (char*)d_ws;
    uint*  hb       = (uint*)ws;  ws += (size_t)ROWPAD * 64 * 4;   // bf16 dinv*h@W (+sentinel)
    uint*  wz       = (uint*)ws;  ws += 3 * 8192 * 4;              // swizzled W ×3
    float* dinv     = (float*)ws; ws += 50016 * 4;
    int*   rowcnt   = (int*)ws;   ws += 50016 * 4;
    int*   rowptr   = (int*)ws;   ws += 50016 * 4;
    int*   rowcur   = (int*)ws;   ws += 50016 * 4;
    int*   csr_src  = (int*)ws;   ws += ((size_t)NEDGES + 64) * 4; // +64 pad for int4 overrun
    int*   bsum     = (int*)ws;   ws += 256 * 4;

    float* out0 = (float*)d_out;                 // [128, 384] pooled
    float* out1 = (float*)d_out + OUT0_ELEMS;    // [50000, 384] per-layer features

    const int nb  = (N + SCAN_CHUNK - 1) / SCAN_CHUNK;  // 98
    const int nbz = 24 + (N + 255) / 256;               // pre: 24 wswz + zero blocks

    k_pre     <<<nbz, 256, 0, stream>>>(W0, W1, W2, wz, rowcnt, hb, N);
    k_count   <<<(E + 255) / 256, 256, 0, stream>>>(dst, rowcnt, E);
    k_sum     <<<nb, 512, 0, stream>>>(rowcnt, bsum, dinv, N);
    k_writeptr<<<nb, 512, 0, stream>>>(rowcnt, bsum, rowptr, rowcur, N, nb);
    k_fill    <<<(E + 255) / 256, 256, 0, stream>>>(src, dst, rowcur, csr_src, E);

    const float* bs[3] = {b0, b1, b2};
    const int ngb = (N + 63) / 64;   // 782 gemm blocks
    for (int l = 0; l < 3; ++l) {
        const float* Ain = (l == 0) ? x : (out1 + (size_t)(l - 1) * DIM);
        int lda          = (l == 0) ? DIM : OUT1_STRIDE;
        k_gemm<<<ngb, 256, 0, stream>>>(Ain, lda, wz + l * 8192, dinv, hb, N);
        k_agg <<<(N + 3) / 4, 256, 0, stream>>>(hb, rowptr, csr_src, dinv,
                                                bs[l], out1, N, l);
    }
    k_pool<<<NGRAPHS * 3, 256, 0, stream>>>(out1, batch, out0, N);
}

// Round 7
// 338.290 us; speedup vs baseline: 1.3004x; 1.0727x over previous
//
#include <hip/hip_runtime.h>

#define NNODES 50000
#define NEDGES 800000
#define DIM 128
#define NGRAPHS 128
#define OUT1_STRIDE 384   // 3 layers * 128 concat along axis 1
#define OUT0_ELEMS (NGRAPHS * OUT1_STRIDE)
#define SCAN_CHUNK 512
#define ROWPAD 50048      // 64-aligned node row allocation (includes sentinel row N)

typedef unsigned int uint;
typedef unsigned short ushort;
typedef short bf16x8 __attribute__((ext_vector_type(8)));
typedef float f32x4 __attribute__((ext_vector_type(4)));
typedef float f32x2 __attribute__((ext_vector_type(2)));  // clang vector: nontemporal-store OK

union U4 { uint4 u; bf16x8 h; };

__device__ inline uint rne_bf16(float f) {
    uint b = __float_as_uint(f);
    return (b + 0x7fffu + ((b >> 16) & 1u)) >> 16;
}
__device__ inline uint pack_bf16(float lo, float hi) {
    return rne_bf16(lo) | (rne_bf16(hi) << 16);
}
__device__ inline float blo(uint u) { return __uint_as_float(u << 16); }
__device__ inline float bhi(uint u) { return __uint_as_float(u & 0xffff0000u); }

// ---------- pre: W swizzle (blocks 0..23) + rowcnt zero + hb sentinel zero ----------
// W -> MFMA B-fragment bf16: frag f = kblk*8+ntile, lane, j:
//   value = W[kblk*32 + (lane>>4)*8 + j][ntile*16 + (lane&15)]
__global__ __launch_bounds__(256) void k_pre(const float* __restrict__ W0,
                                             const float* __restrict__ W1,
                                             const float* __restrict__ W2,
                                             uint* __restrict__ wz,
                                             int* __restrict__ rowcnt,
                                             uint* __restrict__ hb, int N) {
    if (blockIdx.x >= 24) {
        int i = (blockIdx.x - 24) * 256 + threadIdx.x;
        if (i < N) rowcnt[i] = 0;
        if (i < 64) hb[(size_t)N * 64 + i] = 0;  // sentinel row for masked gathers
        return;
    }
    int layer = blockIdx.x >> 3;
    const float* W = (layer == 0) ? W0 : ((layer == 1) ? W1 : W2);
    int t = (blockIdx.x & 7) * 256 + threadIdx.x;  // chunk id 0..2047
    int f = t >> 6, lane = t & 63;
    int kb = f >> 3, nt = f & 7;
    int q = lane >> 4, m = lane & 15;
    int col = nt * 16 + m;
    uint v[8];
#pragma unroll
    for (int j = 0; j < 8; ++j)
        v[j] = rne_bf16(W[(kb * 32 + q * 8 + j) * 128 + col]);
    uint4 o;
    o.x = v[0] | (v[1] << 16);
    o.y = v[2] | (v[3] << 16);
    o.z = v[4] | (v[5] << 16);
    o.w = v[6] | (v[7] << 16);
    ((uint4*)wz)[layer * 2048 + t] = o;
}

// ---------- CSR build (R2 two-pass: atomic-return rank, then non-atomic fill) ----------
__global__ void k_count(const int* __restrict__ dst, int* __restrict__ rowcnt,
                        int* __restrict__ rank, int E) {
    int e = blockIdx.x * blockDim.x + threadIdx.x;
    if (e < E) rank[e] = atomicAdd(&rowcnt[dst[e]], 1);
}

__global__ __launch_bounds__(512) void k_sum(const int* __restrict__ cnt,
                                             int* __restrict__ bsum,
                                             float* __restrict__ dinv, int n) {
    __shared__ int red[512];
    int t = threadIdx.x;
    int i = blockIdx.x * SCAN_CHUNK + t;
    int c = (i < n) ? cnt[i] : 0;
    if (i < n) dinv[i] = rsqrtf((float)c + 1.0f);  // +1 self-loop
    red[t] = c;
    __syncthreads();
    for (int off = 256; off > 0; off >>= 1) {
        if (t < off) red[t] += red[t + off];
        __syncthreads();
    }
    if (t == 0) bsum[blockIdx.x] = red[0];
}

// merged: per-block 512-scan + in-kernel 128-wide bsum scan (replaces k_scanb).
__global__ __launch_bounds__(512) void k_writeptr(const int* __restrict__ cnt,
                                                  const int* __restrict__ bsum,
                                                  int* __restrict__ rowptr,
                                                  int n, int nb) {
    __shared__ int s[512];
    __shared__ int sb[128];
    int t = threadIdx.x;
    if (t < 128) sb[t] = (t < nb) ? bsum[t] : 0;
    __syncthreads();
    for (int off = 1; off < 128; off <<= 1) {
        int u = (t < 128 && t >= off) ? sb[t - off] : 0;
        __syncthreads();
        if (t < 128) sb[t] += u;
        __syncthreads();
    }
    int boffb = (blockIdx.x == 0) ? 0 : sb[blockIdx.x - 1];  // exclusive block offset
    int i = blockIdx.x * SCAN_CHUNK + t;
    int v = (i < n) ? cnt[i] : 0;
    s[t] = v;
    __syncthreads();
    for (int off = 1; off < 512; off <<= 1) {
        int u = (t >= off) ? s[t - off] : 0;
        __syncthreads();
        s[t] += u;
        __syncthreads();
    }
    if (i < n) rowptr[i] = boffb + s[t] - v;
    if (i == n - 1) rowptr[n] = boffb + s[t];
}

__global__ void k_fill(const int* __restrict__ src, const int* __restrict__ dst,
                       const int* __restrict__ rowptr, const int* __restrict__ rank,
                       int* __restrict__ csr_src, int E) {
    int e = blockIdx.x * blockDim.x + threadIdx.x;
    if (e < E) {
        int d = dst[e];
        csr_src[rowptr[d] + rank[e]] = src[e];
    }
}

// ---------- MFMA GEMM: hb[M x 128 bf16] = dinv[row] * (A[M x 128 f32] @ W) ----------
__global__ __launch_bounds__(256) void k_gemm(const float* __restrict__ A, int lda,
                                              const uint* __restrict__ Wswz,
                                              const float* __restrict__ dinv,
                                              uint* __restrict__ hb, int M) {
    __shared__ uint4 wsw[2048];       // 32 KB swizzled W
    __shared__ ushort cbuf[64 * 128]; // 16 KB C bounce
    int tid = threadIdx.x;
#pragma unroll
    for (int i = 0; i < 8; ++i)
        wsw[i * 256 + tid] = ((const uint4*)Wswz)[i * 256 + tid];
    __syncthreads();
    int wave = tid >> 6, lane = tid & 63;
    int q = lane >> 4, m = lane & 15;
    int row0 = blockIdx.x * 64 + wave * 16;
    int arow = min(row0 + m, M - 1);       // clamp; stores are guarded
    const float* Ar = A + (size_t)arow * lda + q * 8;
    f32x4 zero = {0.0f, 0.0f, 0.0f, 0.0f};
    f32x4 acc[8];
#pragma unroll
    for (int i = 0; i < 8; ++i) acc[i] = zero;
#pragma unroll
    for (int kb = 0; kb < 4; ++kb) {
        float4 f0 = *(const float4*)(Ar + kb * 32);
        float4 f1 = *(const float4*)(Ar + kb * 32 + 4);
        U4 a;
        a.u.x = pack_bf16(f0.x, f0.y);
        a.u.y = pack_bf16(f0.z, f0.w);
        a.u.z = pack_bf16(f1.x, f1.y);
        a.u.w = pack_bf16(f1.z, f1.w);
#pragma unroll
        for (int nt = 0; nt < 8; ++nt) {
            U4 b; b.u = wsw[(kb * 8 + nt) * 64 + lane];
            acc[nt] = __builtin_amdgcn_mfma_f32_16x16x32_bf16(a.h, b.h, acc[nt], 0, 0, 0);
        }
    }
    // C/D: col = nt*16 + m, row = q*4 + r ; scale row r by dinv[row0+q*4+r]
    float dv[4];
#pragma unroll
    for (int r = 0; r < 4; ++r)
        dv[r] = dinv[min(row0 + q * 4 + r, M - 1)];
    ushort* cw = cbuf + wave * 16 * 128;
#pragma unroll
    for (int nt = 0; nt < 8; ++nt)
#pragma unroll
        for (int r = 0; r < 4; ++r)
            cw[(q * 4 + r) * 128 + nt * 16 + m] = (ushort)rne_bf16(acc[nt][r] * dv[r]);
    __syncthreads();
    const uint4* cr4 = (const uint4*)cbuf;
#pragma unroll
    for (int i = 0; i < 4; ++i) {
        int c = (wave * 256) + i * 64 + lane;  // chunk: row = c>>4, piece = c&15
        int grow = blockIdx.x * 64 + (c >> 4);
        uint4 v = cr4[c];
        if (grow < M) ((uint4*)hb)[(size_t)grow * 16 + (c & 15)] = v;
    }
}

// ---------- fused aggregate + bias + relu + write out1 ----------
// one wave per node. g16 = lane>>4 edge slot, m16 = lane&15 owns 16B of the 256B
// row. Main loop: 32 edges/iter = 2 int4 idx loads + 8 independent row-gathers in
// flight (MLP). Masked slots read the zeroed sentinel row N.
__global__ __launch_bounds__(256) void k_agg(const uint* __restrict__ hb,
                                             const int* __restrict__ rowptr,
                                             const int* __restrict__ csr_src,
                                             const float* __restrict__ dinv,
                                             const float* __restrict__ bias,
                                             float* __restrict__ out1,
                                             int N, int layer) {
    int wave = threadIdx.x >> 6;
    int lane = threadIdx.x & 63;
    int n = blockIdx.x * 4 + wave;
    if (n >= N) return;
    int g16 = lane >> 4;
    int m16 = lane & 15;
    const uint4* hb4 = (const uint4*)hb;

    int beg = rowptr[n], end = rowptr[n + 1];
    uint4 su = hb4[(size_t)n * 16 + m16];   // self-loop (already dinv[n]-scaled)

    float2 a0, a1, a2, a3;                  // 8 channels as 4 pairs
    float sel = (g16 == 0) ? 1.0f : 0.0f;
    a0 = make_float2(sel * blo(su.x), sel * bhi(su.x));
    a1 = make_float2(sel * blo(su.y), sel * bhi(su.y));
    a2 = make_float2(sel * blo(su.z), sel * bhi(su.z));
    a3 = make_float2(sel * blo(su.w), sel * bhi(su.w));

    const int4* csr4 = (const int4*)csr_src;
    int q0 = beg >> 2;
    int qn = (end + 3) >> 2;                 // one past last quad
    int q = q0;
    for (; q + 8 <= qn; q += 8) {            // 32 edges / iter, 8 gathers in flight
        int qe0 = q + g16;
        int qe1 = q + 4 + g16;
        int4 sva = csr4[qe0];
        int4 svb = csr4[qe1];
        int ea = qe0 * 4, eb = qe1 * 4;
        int s0 = (ea     >= beg && ea     < end) ? sva.x : N;
        int s1 = (ea + 1 >= beg && ea + 1 < end) ? sva.y : N;
        int s2 = (ea + 2 >= beg && ea + 2 < end) ? sva.z : N;
        int s3 = (ea + 3 >= beg && ea + 3 < end) ? sva.w : N;
        int s4 = (eb     >= beg && eb     < end) ? svb.x : N;
        int s5 = (eb + 1 >= beg && eb + 1 < end) ? svb.y : N;
        int s6 = (eb + 2 >= beg && eb + 2 < end) ? svb.z : N;
        int s7 = (eb + 3 >= beg && eb + 3 < end) ? svb.w : N;
        uint4 u0 = hb4[(size_t)s0 * 16 + m16];
        uint4 u1 = hb4[(size_t)s1 * 16 + m16];
        uint4 u2 = hb4[(size_t)s2 * 16 + m16];
        uint4 u3 = hb4[(size_t)s3 * 16 + m16];
        uint4 u4 = hb4[(size_t)s4 * 16 + m16];
        uint4 u5 = hb4[(size_t)s5 * 16 + m16];
        uint4 u6 = hb4[(size_t)s6 * 16 + m16];
        uint4 u7 = hb4[(size_t)s7 * 16 + m16];
        a0.x += blo(u0.x); a0.y += bhi(u0.x);
        a1.x += blo(u0.y); a1.y += bhi(u0.y);
        a2.x += blo(u0.z); a2.y += bhi(u0.z);
        a3.x += blo(u0.w); a3.y += bhi(u0.w);
        a0.x += blo(u1.x); a0.y += bhi(u1.x);
        a1.x += blo(u1.y); a1.y += bhi(u1.y);
        a2.x += blo(u1.z); a2.y += bhi(u1.z);
        a3.x += blo(u1.w); a3.y += bhi(u1.w);
        a0.x += blo(u2.x); a0.y += bhi(u2.x);
        a1.x += blo(u2.y); a1.y += bhi(u2.y);
        a2.x += blo(u2.z); a2.y += bhi(u2.z);
        a3.x += blo(u2.w); a3.y += bhi(u2.w);
        a0.x += blo(u3.x); a0.y += bhi(u3.x);
        a1.x += blo(u3.y); a1.y += bhi(u3.y);
        a2.x += blo(u3.z); a2.y += bhi(u3.z);
        a3.x += blo(u3.w); a3.y += bhi(u3.w);
        a0.x += blo(u4.x); a0.y += bhi(u4.x);
        a1.x += blo(u4.y); a1.y += bhi(u4.y);
        a2.x += blo(u4.z); a2.y += bhi(u4.z);
        a3.x += blo(u4.w); a3.y += bhi(u4.w);
        a0.x += blo(u5.x); a0.y += bhi(u5.x);
        a1.x += blo(u5.y); a1.y += bhi(u5.y);
        a2.x += blo(u5.z); a2.y += bhi(u5.z);
        a3.x += blo(u5.w); a3.y += bhi(u5.w);
        a0.x += blo(u6.x); a0.y += bhi(u6.x);
        a1.x += blo(u6.y); a1.y += bhi(u6.y);
        a2.x += blo(u6.z); a2.y += bhi(u6.z);
        a3.x += blo(u6.w); a3.y += bhi(u6.w);
        a0.x += blo(u7.x); a0.y += bhi(u7.x);
        a1.x += blo(u7.y); a1.y += bhi(u7.y);
        a2.x += blo(u7.z); a2.y += bhi(u7.z);
        a3.x += blo(u7.w); a3.y += bhi(u7.w);
    }
    for (; q < qn; q += 4) {                 // remainder: 16 edges / iter
        int qe = q + g16;
        int4 sv = csr4[qe];
        int e0 = qe * 4;
        int s0 = (e0     >= beg && e0     < end) ? sv.x : N;
        int s1 = (e0 + 1 >= beg && e0 + 1 < end) ? sv.y : N;
        int s2 = (e0 + 2 >= beg && e0 + 2 < end) ? sv.z : N;
        int s3 = (e0 + 3 >= beg && e0 + 3 < end) ? sv.w : N;
        uint4 u0 = hb4[(size_t)s0 * 16 + m16];
        uint4 u1 = hb4[(size_t)s1 * 16 + m16];
        uint4 u2 = hb4[(size_t)s2 * 16 + m16];
        uint4 u3 = hb4[(size_t)s3 * 16 + m16];
        a0.x += blo(u0.x); a0.y += bhi(u0.x);
        a1.x += blo(u0.y); a1.y += bhi(u0.y);
        a2.x += blo(u0.z); a2.y += bhi(u0.z);
        a3.x += blo(u0.w); a3.y += bhi(u0.w);
        a0.x += blo(u1.x); a0.y += bhi(u1.x);
        a1.x += blo(u1.y); a1.y += bhi(u1.y);
        a2.x += blo(u1.z); a2.y += bhi(u1.z);
        a3.x += blo(u1.w); a3.y += bhi(u1.w);
        a0.x += blo(u2.x); a0.y += bhi(u2.x);
        a1.x += blo(u2.y); a1.y += bhi(u2.y);
        a2.x += blo(u2.z); a2.y += bhi(u2.z);
        a3.x += blo(u2.w); a3.y += bhi(u2.w);
        a0.x += blo(u3.x); a0.y += bhi(u3.x);
        a1.x += blo(u3.y); a1.y += bhi(u3.y);
        a2.x += blo(u3.z); a2.y += bhi(u3.z);
        a3.x += blo(u3.w); a3.y += bhi(u3.w);
    }

    // cross-slot reduce: groups 0..3 hold partials of the same 8 channels
#pragma unroll
    for (int d = 16; d < 64; d <<= 1) {
        a0.x += __shfl_xor(a0.x, d); a0.y += __shfl_xor(a0.y, d);
        a1.x += __shfl_xor(a1.x, d); a1.y += __shfl_xor(a1.y, d);
        a2.x += __shfl_xor(a2.x, d); a2.y += __shfl_xor(a2.y, d);
        a3.x += __shfl_xor(a3.x, d); a3.y += __shfl_xor(a3.y, d);
    }

    // lane writes channel pair c = m16*8 + g16*2
    float2 pr = (g16 == 0) ? a0 : (g16 == 1) ? a1 : (g16 == 2) ? a2 : a3;
    float din = dinv[n];
    float2 b = ((const float2*)bias)[m16 * 4 + g16];
    f32x2 o;
    o.x = fmaxf(din * pr.x + b.x, 0.0f);
    o.y = fmaxf(din * pr.y + b.y, 0.0f);
    size_t o1 = (size_t)n * OUT1_STRIDE + layer * DIM + (m16 * 8 + g16 * 2);
    __builtin_nontemporal_store(o, (f32x2*)(out1 + o1));
}

// ---------- mean-pool: 3 blocks per graph (128-ch chunk each), 2 row-slices ----------
__global__ __launch_bounds__(256) void k_pool(const float* __restrict__ out1,
                                              const int* __restrict__ batch,
                                              float* __restrict__ out0, int N) {
    int g = blockIdx.x / 3;
    int chunk = blockIdx.x % 3;
    int lo = 0, hi = N;
    while (lo < hi) { int mid = (lo + hi) >> 1; if (batch[mid] < g) lo = mid + 1; else hi = mid; }
    int beg = lo;
    hi = N;
    while (lo < hi) { int mid = (lo + hi) >> 1; if (batch[mid] < g + 1) lo = mid + 1; else hi = mid; }
    int end = lo;
    int t = threadIdx.x;
    int ch = t & 127;
    int slice = t >> 7;            // 0 or 1: even/odd rows
    const float* p = out1 + (size_t)chunk * 128 + ch;
    float acc = 0.0f;
    int i = beg + slice;
    for (; i + 6 < end; i += 8) {  // stride-2 rows, 4-way MLP unroll
        float a0 = p[(size_t)i * OUT1_STRIDE];
        float a1 = p[(size_t)(i + 2) * OUT1_STRIDE];
        float a2 = p[(size_t)(i + 4) * OUT1_STRIDE];
        float a3 = p[(size_t)(i + 6) * OUT1_STRIDE];
        acc += (a0 + a1) + (a2 + a3);
    }
    for (; i < end; i += 2) acc += p[(size_t)i * OUT1_STRIDE];
    __shared__ float red[256];
    red[t] = acc;
    __syncthreads();
    if (t < 128) {
        float tot = red[t] + red[t + 128];
        float cnt = (float)(end - beg);
        out0[(size_t)g * OUT1_STRIDE + chunk * 128 + t] = tot / fmaxf(cnt, 1.0f);
    }
}

extern "C" void kernel_launch(void* const* d_in, const int* in_sizes, int n_in,
                              void* d_out, int out_size, void* d_ws, size_t ws_size,
                              hipStream_t stream) {
    const float* x     = (const float*)d_in[0];
    const int*   ei    = (const int*)d_in[1];
    const int*   batch = (const int*)d_in[2];
    const float* W0 = (const float*)d_in[3];
    const float* b0 = (const float*)d_in[4];
    const float* W1 = (const float*)d_in[5];
    const float* b1 = (const float*)d_in[6];
    const float* W2 = (const float*)d_in[7];
    const float* b2 = (const float*)d_in[8];
    (void)n_in; (void)ws_size; (void)out_size;

    const int E = in_sizes[1] / 2;
    const int N = in_sizes[2];
    const int* src = ei;
    const int* dst = ei + E;

    char* ws = (char*)d_ws;
    uint*  hb       = (uint*)ws;  ws += (size_t)ROWPAD * 64 * 4;   // bf16 dinv*h@W (+sentinel)
    uint*  wz       = (uint*)ws;  ws += 3 * 8192 * 4;              // swizzled W ×3
    float* dinv     = (float*)ws; ws += 50016 * 4;
    int*   rowcnt   = (int*)ws;   ws += 50016 * 4;
    int*   rowptr   = (int*)ws;   ws += 50016 * 4;
    int*   rank     = (int*)ws;   ws += (size_t)NEDGES * 4;
    int*   csr_src  = (int*)ws;   ws += ((size_t)NEDGES + 64) * 4; // +64 pad for int4 overrun
    int*   bsum     = (int*)ws;   ws += 256 * 4;

    float* out0 = (float*)d_out;                 // [128, 384] pooled
    float* out1 = (float*)d_out + OUT0_ELEMS;    // [50000, 384] per-layer features

    const int nb  = (N + SCAN_CHUNK - 1) / SCAN_CHUNK;  // 98
    const int nbz = 24 + (N + 255) / 256;               // pre: 24 wswz + zero blocks

    k_pre     <<<nbz, 256, 0, stream>>>(W0, W1, W2, wz, rowcnt, hb, N);
    k_count   <<<(E + 255) / 256, 256, 0, stream>>>(dst, rowcnt, rank, E);
    k_sum     <<<nb, 512, 0, stream>>>(rowcnt, bsum, dinv, N);
    k_writeptr<<<nb, 512, 0, stream>>>(rowcnt, bsum, rowptr, N, nb);
    k_fill    <<<(E + 255) / 256, 256, 0, stream>>>(src, dst, rowptr, rank, csr_src, E);

    const float* bs[3] = {b0, b1, b2};
    const int ngb = (N + 63) / 64;   // 782 gemm blocks
    for (int l = 0; l < 3; ++l) {
        const float* Ain = (l == 0) ? x : (out1 + (size_t)(l - 1) * DIM);
        int lda          = (l == 0) ? DIM : OUT1_STRIDE;
        k_gemm<<<ngb, 256, 0, stream>>>(Ain, lda, wz + l * 8192, dinv, hb, N);
        k_agg <<<(N + 3) / 4, 256, 0, stream>>>(hb, rowptr, csr_src, dinv,
                                                bs[l], out1, N, l);
    }
    k_pool<<<NGRAPHS * 3, 256, 0, stream>>>(out1, batch, out0, N);
}

// Round 8
// 309.822 us; speedup vs baseline: 1.4199x; 1.0919x over previous
//
#include <hip/hip_runtime.h>

#define NNODES 50000
#define NEDGES 800000
#define DIM 128
#define NGRAPHS 128
#define OUT1_STRIDE 384   // 3 layers * 128 concat along axis 1
#define OUT0_ELEMS (NGRAPHS * OUT1_STRIDE)
#define SCAN_CHUNK 512
#define ROWPAD 50048      // 64-aligned node row allocation (includes sentinel row N)

typedef unsigned int uint;
typedef unsigned short ushort;
typedef short bf16x8 __attribute__((ext_vector_type(8)));
typedef float f32x4 __attribute__((ext_vector_type(4)));

union U4 { uint4 u; bf16x8 h; };

__device__ inline uint rne_bf16(float f) {
    uint b = __float_as_uint(f);
    return (b + 0x7fffu + ((b >> 16) & 1u)) >> 16;
}
__device__ inline uint pack_bf16(float lo, float hi) {
    return rne_bf16(lo) | (rne_bf16(hi) << 16);
}
__device__ inline float blo(uint u) { return __uint_as_float(u << 16); }
__device__ inline float bhi(uint u) { return __uint_as_float(u & 0xffff0000u); }

// ---------- pre: W swizzle (blocks 0..23) + rowcnt zero + hb sentinel zero ----------
// W -> MFMA B-fragment bf16: frag f = kblk*8+ntile, lane, j:
//   value = W[kblk*32 + (lane>>4)*8 + j][ntile*16 + (lane&15)]
__global__ __launch_bounds__(256) void k_pre(const float* __restrict__ W0,
                                             const float* __restrict__ W1,
                                             const float* __restrict__ W2,
                                             uint* __restrict__ wz,
                                             int* __restrict__ rowcnt,
                                             uint* __restrict__ hb, int N) {
    if (blockIdx.x >= 24) {
        int i = (blockIdx.x - 24) * 256 + threadIdx.x;
        if (i < N) rowcnt[i] = 0;
        if (i < 64) hb[(size_t)N * 64 + i] = 0;  // sentinel row for masked gathers
        return;
    }
    int layer = blockIdx.x >> 3;
    const float* W = (layer == 0) ? W0 : ((layer == 1) ? W1 : W2);
    int t = (blockIdx.x & 7) * 256 + threadIdx.x;  // chunk id 0..2047
    int f = t >> 6, lane = t & 63;
    int kb = f >> 3, nt = f & 7;
    int q = lane >> 4, m = lane & 15;
    int col = nt * 16 + m;
    uint v[8];
#pragma unroll
    for (int j = 0; j < 8; ++j)
        v[j] = rne_bf16(W[(kb * 32 + q * 8 + j) * 128 + col]);
    uint4 o;
    o.x = v[0] | (v[1] << 16);
    o.y = v[2] | (v[3] << 16);
    o.z = v[4] | (v[5] << 16);
    o.w = v[6] | (v[7] << 16);
    ((uint4*)wz)[layer * 2048 + t] = o;
}

// ---------- CSR build (two-pass: atomic-return rank, then non-atomic fill) ----------
__global__ void k_count(const int* __restrict__ dst, int* __restrict__ rowcnt,
                        int* __restrict__ rank, int E) {
    int e = blockIdx.x * blockDim.x + threadIdx.x;
    if (e < E) rank[e] = atomicAdd(&rowcnt[dst[e]], 1);
}

__global__ __launch_bounds__(512) void k_sum(const int* __restrict__ cnt,
                                             int* __restrict__ bsum,
                                             float* __restrict__ dinv, int n) {
    __shared__ int red[512];
    int t = threadIdx.x;
    int i = blockIdx.x * SCAN_CHUNK + t;
    int c = (i < n) ? cnt[i] : 0;
    if (i < n) dinv[i] = rsqrtf((float)c + 1.0f);  // +1 self-loop
    red[t] = c;
    __syncthreads();
    for (int off = 256; off > 0; off >>= 1) {
        if (t < off) red[t] += red[t + off];
        __syncthreads();
    }
    if (t == 0) bsum[blockIdx.x] = red[0];
}

// merged: per-block 512-scan + in-kernel 128-wide bsum scan (replaces k_scanb).
__global__ __launch_bounds__(512) void k_writeptr(const int* __restrict__ cnt,
                                                  const int* __restrict__ bsum,
                                                  int* __restrict__ rowptr,
                                                  int n, int nb) {
    __shared__ int s[512];
    __shared__ int sb[128];
    int t = threadIdx.x;
    if (t < 128) sb[t] = (t < nb) ? bsum[t] : 0;
    __syncthreads();
    for (int off = 1; off < 128; off <<= 1) {
        int u = (t < 128 && t >= off) ? sb[t - off] : 0;
        __syncthreads();
        if (t < 128) sb[t] += u;
        __syncthreads();
    }
    int boffb = (blockIdx.x == 0) ? 0 : sb[blockIdx.x - 1];  // exclusive block offset
    int i = blockIdx.x * SCAN_CHUNK + t;
    int v = (i < n) ? cnt[i] : 0;
    s[t] = v;
    __syncthreads();
    for (int off = 1; off < 512; off <<= 1) {
        int u = (t >= off) ? s[t - off] : 0;
        __syncthreads();
        s[t] += u;
        __syncthreads();
    }
    if (i < n) rowptr[i] = boffb + s[t] - v;
    if (i == n - 1) rowptr[n] = boffb + s[t];
}

__global__ void k_fill(const int* __restrict__ src, const int* __restrict__ dst,
                       const int* __restrict__ rowptr, const int* __restrict__ rank,
                       int* __restrict__ csr_src, int E) {
    int e = blockIdx.x * blockDim.x + threadIdx.x;
    if (e < E) {
        int d = dst[e];
        csr_src[rowptr[d] + rank[e]] = src[e];
    }
}

// ---------- MFMA GEMM: hb[M x 128 bf16] = dinv[row] * (A[M x 128 f32] @ W) ----------
__global__ __launch_bounds__(256) void k_gemm(const float* __restrict__ A, int lda,
                                              const uint* __restrict__ Wswz,
                                              const float* __restrict__ dinv,
                                              uint* __restrict__ hb, int M) {
    __shared__ uint4 wsw[2048];       // 32 KB swizzled W
    __shared__ ushort cbuf[64 * 128]; // 16 KB C bounce
    int tid = threadIdx.x;
#pragma unroll
    for (int i = 0; i < 8; ++i)
        wsw[i * 256 + tid] = ((const uint4*)Wswz)[i * 256 + tid];
    __syncthreads();
    int wave = tid >> 6, lane = tid & 63;
    int q = lane >> 4, m = lane & 15;
    int row0 = blockIdx.x * 64 + wave * 16;
    int arow = min(row0 + m, M - 1);       // clamp; stores are guarded
    const float* Ar = A + (size_t)arow * lda + q * 8;
    f32x4 zero = {0.0f, 0.0f, 0.0f, 0.0f};
    f32x4 acc[8];
#pragma unroll
    for (int i = 0; i < 8; ++i) acc[i] = zero;
#pragma unroll
    for (int kb = 0; kb < 4; ++kb) {
        float4 f0 = *(const float4*)(Ar + kb * 32);
        float4 f1 = *(const float4*)(Ar + kb * 32 + 4);
        U4 a;
        a.u.x = pack_bf16(f0.x, f0.y);
        a.u.y = pack_bf16(f0.z, f0.w);
        a.u.z = pack_bf16(f1.x, f1.y);
        a.u.w = pack_bf16(f1.z, f1.w);
#pragma unroll
        for (int nt = 0; nt < 8; ++nt) {
            U4 b; b.u = wsw[(kb * 8 + nt) * 64 + lane];
            acc[nt] = __builtin_amdgcn_mfma_f32_16x16x32_bf16(a.h, b.h, acc[nt], 0, 0, 0);
        }
    }
    // C/D: col = nt*16 + m, row = q*4 + r ; scale row r by dinv[row0+q*4+r]
    float dv[4];
#pragma unroll
    for (int r = 0; r < 4; ++r)
        dv[r] = dinv[min(row0 + q * 4 + r, M - 1)];
    ushort* cw = cbuf + wave * 16 * 128;
#pragma unroll
    for (int nt = 0; nt < 8; ++nt)
#pragma unroll
        for (int r = 0; r < 4; ++r)
            cw[(q * 4 + r) * 128 + nt * 16 + m] = (ushort)rne_bf16(acc[nt][r] * dv[r]);
    __syncthreads();
    const uint4* cr4 = (const uint4*)cbuf;
#pragma unroll
    for (int i = 0; i < 4; ++i) {
        int c = (wave * 256) + i * 64 + lane;  // chunk: row = c>>4, piece = c&15
        int grow = blockIdx.x * 64 + (c >> 4);
        uint4 v = cr4[c];
        if (grow < M) ((uint4*)hb)[(size_t)grow * 16 + (c & 15)] = v;
    }
}

// ---------- fused aggregate + bias + relu + write out1 (R2-proven form) ----------
// one wave per node. Lane layout: g16 = lane>>4 owns edge slot, m16 = lane&15 owns
// 8 channels (one uint4 = 16B of the 256B row). One gather instruction covers
// 4 edges x full row; NO cross-lane shuffles in the edge loop. Out-of-range edge
// slots read the zeroed sentinel row (index N).
__global__ __launch_bounds__(256) void k_agg(const uint* __restrict__ hb,
                                             const int* __restrict__ rowptr,
                                             const int* __restrict__ csr_src,
                                             const float* __restrict__ dinv,
                                             const float* __restrict__ bias,
                                             float* __restrict__ out1,
                                             int N, int layer) {
    int wave = threadIdx.x >> 6;
    int lane = threadIdx.x & 63;
    int n = blockIdx.x * 4 + wave;
    if (n >= N) return;
    int g16 = lane >> 4;
    int m16 = lane & 15;
    const uint4* hb4 = (const uint4*)hb;

    // self-loop: hb already holds dinv[n]*h[n]; count it once (group 0 only)
    uint4 su = hb4[(size_t)n * 16 + m16];
    float sel = (g16 == 0) ? 1.0f : 0.0f;
    float a0 = sel * blo(su.x), a1 = sel * bhi(su.x);
    float a2 = sel * blo(su.y), a3 = sel * bhi(su.y);
    float a4 = sel * blo(su.z), a5 = sel * bhi(su.z);
    float a6 = sel * blo(su.w), a7 = sel * bhi(su.w);

    int beg = rowptr[n], end = rowptr[n + 1];
    for (int base = beg; base < end; base += 16) {
        int s0, s1, s2, s3;
        {
            int e0 = base + 0 + g16;
            int e1 = base + 4 + g16;
            int e2 = base + 8 + g16;
            int e3 = base + 12 + g16;
            s0 = (e0 < end) ? csr_src[e0] : N;
            s1 = (e1 < end) ? csr_src[min(e1, end - 1)] : N;
            s2 = (e2 < end) ? csr_src[min(e2, end - 1)] : N;
            s3 = (e3 < end) ? csr_src[min(e3, end - 1)] : N;
        }
        uint4 u0 = hb4[(size_t)s0 * 16 + m16];
        uint4 u1 = hb4[(size_t)s1 * 16 + m16];
        uint4 u2 = hb4[(size_t)s2 * 16 + m16];
        uint4 u3 = hb4[(size_t)s3 * 16 + m16];
        a0 += blo(u0.x); a1 += bhi(u0.x); a2 += blo(u0.y); a3 += bhi(u0.y);
        a4 += blo(u0.z); a5 += bhi(u0.z); a6 += blo(u0.w); a7 += bhi(u0.w);
        a0 += blo(u1.x); a1 += bhi(u1.x); a2 += blo(u1.y); a3 += bhi(u1.y);
        a4 += blo(u1.z); a5 += bhi(u1.z); a6 += blo(u1.w); a7 += bhi(u1.w);
        a0 += blo(u2.x); a1 += bhi(u2.x); a2 += blo(u2.y); a3 += bhi(u2.y);
        a4 += blo(u2.z); a5 += bhi(u2.z); a6 += blo(u2.w); a7 += bhi(u2.w);
        a0 += blo(u3.x); a1 += bhi(u3.x); a2 += blo(u3.y); a3 += bhi(u3.y);
        a4 += blo(u3.z); a5 += bhi(u3.z); a6 += blo(u3.w); a7 += bhi(u3.w);
    }

    // cross-group reduce: groups 0..3 hold partial sums of the same 8 channels
#pragma unroll
    for (int d = 16; d < 64; d <<= 1) {
        a0 += __shfl_xor(a0, d); a1 += __shfl_xor(a1, d);
        a2 += __shfl_xor(a2, d); a3 += __shfl_xor(a3, d);
        a4 += __shfl_xor(a4, d); a5 += __shfl_xor(a5, d);
        a6 += __shfl_xor(a6, d); a7 += __shfl_xor(a7, d);
    }

    // lane writes channel pair c = m16*8 + g16*2  (compile-time acc selection)
    float vx = (g16 == 0) ? a0 : (g16 == 1) ? a2 : (g16 == 2) ? a4 : a6;
    float vy = (g16 == 0) ? a1 : (g16 == 1) ? a3 : (g16 == 2) ? a5 : a7;
    float din = dinv[n];
    float2 b = ((const float2*)bias)[m16 * 4 + g16];
    float ox = fmaxf(din * vx + b.x, 0.0f);
    float oy = fmaxf(din * vy + b.y, 0.0f);
    size_t o1 = (size_t)n * OUT1_STRIDE + layer * DIM + (m16 * 8 + g16 * 2);
    *(float2*)(out1 + o1) = make_float2(ox, oy);
}

// ---------- mean-pool: 3 blocks per graph (128-ch chunk each), 2 row-slices ----------
__global__ __launch_bounds__(256) void k_pool(const float* __restrict__ out1,
                                              const int* __restrict__ batch,
                                              float* __restrict__ out0, int N) {
    int g = blockIdx.x / 3;
    int chunk = blockIdx.x % 3;
    int lo = 0, hi = N;
    while (lo < hi) { int mid = (lo + hi) >> 1; if (batch[mid] < g) lo = mid + 1; else hi = mid; }
    int beg = lo;
    hi = N;
    while (lo < hi) { int mid = (lo + hi) >> 1; if (batch[mid] < g + 1) lo = mid + 1; else hi = mid; }
    int end = lo;
    int t = threadIdx.x;
    int ch = t & 127;
    int slice = t >> 7;            // 0 or 1: even/odd rows
    const float* p = out1 + (size_t)chunk * 128 + ch;
    float acc = 0.0f;
    int i = beg + slice;
    for (; i + 6 < end; i += 8) {  // stride-2 rows, 4-way MLP unroll
        float a0 = p[(size_t)i * OUT1_STRIDE];
        float a1 = p[(size_t)(i + 2) * OUT1_STRIDE];
        float a2 = p[(size_t)(i + 4) * OUT1_STRIDE];
        float a3 = p[(size_t)(i + 6) * OUT1_STRIDE];
        acc += (a0 + a1) + (a2 + a3);
    }
    for (; i < end; i += 2) acc += p[(size_t)i * OUT1_STRIDE];
    __shared__ float red[256];
    red[t] = acc;
    __syncthreads();
    if (t < 128) {
        float tot = red[t] + red[t + 128];
        float cnt = (float)(end - beg);
        out0[(size_t)g * OUT1_STRIDE + chunk * 128 + t] = tot / fmaxf(cnt, 1.0f);
    }
}

extern "C" void kernel_launch(void* const* d_in, const int* in_sizes, int n_in,
                              void* d_out, int out_size, void* d_ws, size_t ws_size,
                              hipStream_t stream) {
    const float* x     = (const float*)d_in[0];
    const int*   ei    = (const int*)d_in[1];
    const int*   batch = (const int*)d_in[2];
    const float* W0 = (const float*)d_in[3];
    const float* b0 = (const float*)d_in[4];
    const float* W1 = (const float*)d_in[5];
    const float* b1 = (const float*)d_in[6];
    const float* W2 = (const float*)d_in[7];
    const float* b2 = (const float*)d_in[8];
    (void)n_in; (void)ws_size; (void)out_size;

    const int E = in_sizes[1] / 2;
    const int N = in_sizes[2];
    const int* src = ei;
    const int* dst = ei + E;

    char* ws = (char*)d_ws;
    uint*  hb       = (uint*)ws;  ws += (size_t)ROWPAD * 64 * 4;   // bf16 dinv*h@W (+sentinel)
    uint*  wz       = (uint*)ws;  ws += 3 * 8192 * 4;              // swizzled W ×3
    float* dinv     = (float*)ws; ws += 50016 * 4;
    int*   rowcnt   = (int*)ws;   ws += 50016 * 4;
    int*   rowptr   = (int*)ws;   ws += 50016 * 4;
    int*   rank     = (int*)ws;   ws += (size_t)NEDGES * 4;
    int*   csr_src  = (int*)ws;   ws += (size_t)NEDGES * 4;
    int*   bsum     = (int*)ws;   ws += 256 * 4;

    float* out0 = (float*)d_out;                 // [128, 384] pooled
    float* out1 = (float*)d_out + OUT0_ELEMS;    // [50000, 384] per-layer features

    const int nb  = (N + SCAN_CHUNK - 1) / SCAN_CHUNK;  // 98
    const int nbz = 24 + (N + 255) / 256;               // pre: 24 wswz + zero blocks

    k_pre     <<<nbz, 256, 0, stream>>>(W0, W1, W2, wz, rowcnt, hb, N);
    k_count   <<<(E + 255) / 256, 256, 0, stream>>>(dst, rowcnt, rank, E);
    k_sum     <<<nb, 512, 0, stream>>>(rowcnt, bsum, dinv, N);
    k_writeptr<<<nb, 512, 0, stream>>>(rowcnt, bsum, rowptr, N, nb);
    k_fill    <<<(E + 255) / 256, 256, 0, stream>>>(src, dst, rowptr, rank, csr_src, E);

    const float* bs[3] = {b0, b1, b2};
    const int ngb = (N + 63) / 64;   // 782 gemm blocks
    for (int l = 0; l < 3; ++l) {
        const float* Ain = (l == 0) ? x : (out1 + (size_t)(l - 1) * DIM);
        int lda          = (l == 0) ? DIM : OUT1_STRIDE;
        k_gemm<<<ngb, 256, 0, stream>>>(Ain, lda, wz + l * 8192, dinv, hb, N);
        k_agg <<<(N + 3) / 4, 256, 0, stream>>>(hb, rowptr, csr_src, dinv,
                                                bs[l], out1, N, l);
    }
    k_pool<<<NGRAPHS * 3, 256, 0, stream>>>(out1, batch, out0, N);
}